// Round 6
// baseline (1834.465 us; speedup 1.0000x reference)
//
#include <hip/hip_runtime.h>

// Problem constants
#define Bq 1024
#define Tq 512
#define Fq 64    // input features
#define Hq 128   // hidden

typedef _Float16 f16;
typedef f16 f16x4 __attribute__((ext_vector_type(4)));
typedef f16 f16x8 __attribute__((ext_vector_type(8)));
typedef float f32x4 __attribute__((ext_vector_type(4)));

__device__ __forceinline__ float sigmoidf_(float x) {
    return 1.f / (1.f + __expf(-x));
}
__device__ __forceinline__ float tanhf_(float x) {
    return 1.f - 2.f / (__expf(2.f * x) + 1.f);
}

// 256 blocks x 512 threads (8 waves), 4 batch rows per block.
// Encoder: gates via mfma_f32_16x16x32_f16, M=512 gates (8 waves x 4 tiles:
// wave w owns tiles {w,8+w,16+w,24+w} = i,f,g,o of units 16w..16w+15),
// N=16 (4 real batch cols), K=192 (2 x-tiles + 4 h-tiles).
// KEY: D-layout lane (n16<4, kg) holds ALL FOUR gates of units
// wv*16+kg*4+r in acc[0..3][r] -> nonlinearity directly on MFMA output,
// NO LDS bounce. c in registers, h straight to double-buffered hT.
// x staged in 8-step chunks (HBM latency hidden under 8 steps).
// Decoder: x_dec = h@Wout^T + b_out is LINEAR in h -> fold:
//   W_comb = W_ih_dec@W_out + W_hh_dec  (512x128), K=128 only, no x.
// Projection (for rec_err only, off the recurrence) runs concurrently on
// waves 4..7 as A=W_out MFMA. ONE barrier per step everywhere.
// Frag layouts (validated rounds 4-5):
//   A: lane l holds A[l&15][(l>>4)*8+j]   B: lane l holds B[(l>>4)*8+j][l&15]
//   D: lane l reg r = D[(l>>4)*4+r][l&15]
__global__ __launch_bounds__(512, 2) void lstm_ae_kernel(
    const float* __restrict__ ts,
    const float* __restrict__ Wih_e, const float* __restrict__ Whh_e,
    const float* __restrict__ bih_e, const float* __restrict__ bhh_e,
    const float* __restrict__ Wih_d, const float* __restrict__ Whh_d,
    const float* __restrict__ bih_d, const float* __restrict__ bhh_d,
    const float* __restrict__ Wout, const float* __restrict__ bout,
    float* __restrict__ out)
{
    const int tid = threadIdx.x;
    const int bid = blockIdx.x;
    const int row0 = bid * 4;

    const int wv = tid >> 6;       // wave 0..7
    const int ln = tid & 63;
    const int n16 = ln & 15;       // MFMA N col (batch col; <4 real)
    const int kg = ln >> 4;        // k-group 0..3
    const int zr = n16 & 3;        // aliased batch row for B-fragment
    const bool act = (n16 < 4);

    __shared__ alignas(16) f16 hT[2][4][136];        // h dbuf, 2.2 KB
    __shared__ alignas(16) f16 xS[2][4][8][72];      // x chunk dbuf, 9 KB
    __shared__ float errb[4][4];

    float c_[4] = {0.f, 0.f, 0.f, 0.f};
    float bias_[4][4];

    // ===================== encoder setup =====================
    f16x8 wf[4][6];   // A-frags [gate][k-tile], 96 VGPR
#pragma unroll
    for (int g = 0; g < 4; ++g) {
        const int gr = g * 128 + wv * 16 + n16;
#pragma unroll
        for (int kt = 0; kt < 6; ++kt) {
            const int kc = kt * 32 + kg * 8;
            const float* src = (kt < 2)
                ? (Wih_e + (size_t)gr * Fq + kc)
                : (Whh_e + (size_t)gr * Hq + (kc - 64));
            float4 f0 = *(const float4*)src;
            float4 f1 = *(const float4*)(src + 4);
            f16x8 a;
            a[0] = (f16)f0.x; a[1] = (f16)f0.y; a[2] = (f16)f0.z; a[3] = (f16)f0.w;
            a[4] = (f16)f1.x; a[5] = (f16)f1.y; a[6] = (f16)f1.z; a[7] = (f16)f1.w;
            wf[g][kt] = a;
        }
#pragma unroll
        for (int r = 0; r < 4; ++r) {
            const int u = g * 128 + wv * 16 + kg * 4 + r;
            bias_[g][r] = bih_e[u] + bhh_e[u];
        }
    }

    // zero h buffer 0 (same pattern as cell h-write)
    if (act) {
        f16x4 z; z[0] = (f16)0.f; z[1] = (f16)0.f; z[2] = (f16)0.f; z[3] = (f16)0.f;
        *(f16x4*)(&hT[0][n16][wv * 16 + kg * 4]) = z;
    }
    // stage x chunk 0: thread -> (r, t8, fg)
    const int sr = tid >> 7, st8 = (tid >> 4) & 7, sfg = tid & 15;
    {
        float4 v = *(const float4*)(ts + (size_t)(row0 + sr) * Tq * Fq +
                                    (size_t)st8 * Fq + sfg * 4);
        f16x4 h4; h4[0] = (f16)v.x; h4[1] = (f16)v.y; h4[2] = (f16)v.z; h4[3] = (f16)v.w;
        *(f16x4*)(&xS[0][sr][st8][sfg * 4]) = h4;
    }
    __syncthreads();

    // ===================== encoder: 512 steps, 1 barrier each ============
    float4 xpre;
    for (int t = 0; t < Tq; ++t) {
        const int buf = (t >> 3) & 1, tb = t & 7, par = t & 1;
        if (tb == 0 && t < Tq - 8) {   // issue chunk c+1 loads (hidden 8 steps)
            xpre = *(const float4*)(ts + (size_t)(row0 + sr) * Tq * Fq +
                                    (size_t)(t + 8 + st8) * Fq + sfg * 4);
        }
        // cell
        f16x8 bf[6];
        bf[0] = *(const f16x8*)(&xS[buf][zr][tb][kg * 8]);
        bf[1] = *(const f16x8*)(&xS[buf][zr][tb][32 + kg * 8]);
#pragma unroll
        for (int kt = 0; kt < 4; ++kt)
            bf[2 + kt] = *(const f16x8*)(&hT[par][zr][kt * 32 + kg * 8]);
        f32x4 acc[4];
#pragma unroll
        for (int g = 0; g < 4; ++g) acc[g] = (f32x4){0.f, 0.f, 0.f, 0.f};
#pragma unroll
        for (int kt = 0; kt < 6; ++kt)
#pragma unroll
            for (int g = 0; g < 4; ++g)
                acc[g] = __builtin_amdgcn_mfma_f32_16x16x32_f16(
                    wf[g][kt], bf[kt], acc[g], 0, 0, 0);
        if (act) {   // nonlinearity directly in D-layout: 4 units per lane
            f16x4 h4;
#pragma unroll
            for (int r = 0; r < 4; ++r) {
                float i_ = sigmoidf_(acc[0][r] + bias_[0][r]);
                float f_ = sigmoidf_(acc[1][r] + bias_[1][r]);
                float g_ = tanhf_(acc[2][r] + bias_[2][r]);
                float o_ = sigmoidf_(acc[3][r] + bias_[3][r]);
                c_[r] = f_ * c_[r] + i_ * g_;
                h4[r] = (f16)(o_ * tanhf_(c_[r]));
            }
            *(f16x4*)(&hT[par ^ 1][n16][wv * 16 + kg * 4]) = h4;
        }
        if (tb == 7 && t != Tq - 1) {  // publish staged chunk
            f16x4 h4; h4[0] = (f16)xpre.x; h4[1] = (f16)xpre.y;
            h4[2] = (f16)xpre.z; h4[3] = (f16)xpre.w;
            *(f16x4*)(&xS[buf ^ 1][sr][st8][sfg * 4]) = h4;
        }
        __syncthreads();
    }

    // c_enc: lane (n16<4, kg) owns units wv*16+kg*4+0..3 of batch row n16
    if (act) {
        float4 c4; c4.x = c_[0]; c4.y = c_[1]; c4.z = c_[2]; c4.w = c_[3];
        *(float4*)(out + (size_t)(row0 + n16) * Hq + wv * 16 + kg * 4) = c4;
    }

    // ===================== decoder setup (fold) =====================
    // W_comb = W_ih_dec @ W_out + W_hh_dec; b_fold = b_ih+b_hh+W_ih_dec@b_out
    f16x8 wc[4][4];   // 64 VGPR
#pragma unroll
    for (int g = 0; g < 4; ++g) {
        const int gr = g * 128 + wv * 16 + n16;
        float fa[4][8];
#pragma unroll
        for (int kt = 0; kt < 4; ++kt)
#pragma unroll
            for (int jj = 0; jj < 8; ++jj) fa[kt][jj] = 0.f;
        for (int f = 0; f < Fq; ++f) {
            float wv_ = Wih_d[(size_t)gr * Fq + f];
#pragma unroll
            for (int kt = 0; kt < 4; ++kt) {
                float4 o0 = *(const float4*)(Wout + (size_t)f * Hq + kt * 32 + kg * 8);
                float4 o1 = *(const float4*)(Wout + (size_t)f * Hq + kt * 32 + kg * 8 + 4);
                fa[kt][0] += wv_ * o0.x; fa[kt][1] += wv_ * o0.y;
                fa[kt][2] += wv_ * o0.z; fa[kt][3] += wv_ * o0.w;
                fa[kt][4] += wv_ * o1.x; fa[kt][5] += wv_ * o1.y;
                fa[kt][6] += wv_ * o1.z; fa[kt][7] += wv_ * o1.w;
            }
        }
#pragma unroll
        for (int kt = 0; kt < 4; ++kt) {
            f16x8 a;
#pragma unroll
            for (int jj = 0; jj < 8; ++jj)
                a[jj] = (f16)(fa[kt][jj] +
                              Whh_d[(size_t)gr * Hq + kt * 32 + kg * 8 + jj]);
            wc[g][kt] = a;
        }
#pragma unroll
        for (int r = 0; r < 4; ++r) {
            const int u = g * 128 + wv * 16 + kg * 4 + r;
            float b = bih_d[u] + bhh_d[u];
            for (int f = 0; f < Fq; ++f)
                b += Wih_d[(size_t)u * Fq + f] * bout[f];
            bias_[g][r] = b;
        }
    }
    // proj A-frags (waves 4..7 use them; mt=wv&3 keeps addresses valid)
    const int mt = wv & 3;
    f16x8 wo[4];
#pragma unroll
    for (int kt = 0; kt < 4; ++kt) {
        const float* src = Wout + (size_t)(mt * 16 + n16) * Hq + kt * 32 + kg * 8;
        float4 f0 = *(const float4*)src;
        float4 f1 = *(const float4*)(src + 4);
        f16x8 a;
        a[0] = (f16)f0.x; a[1] = (f16)f0.y; a[2] = (f16)f0.z; a[3] = (f16)f0.w;
        a[4] = (f16)f1.x; a[5] = (f16)f1.y; a[6] = (f16)f1.z; a[7] = (f16)f1.w;
        wo[kt] = a;
    }
    float4 bo4 = *(const float4*)(bout + mt * 16 + kg * 4);
    float4 tsv = *(const float4*)(ts + (size_t)(row0 + zr) * Tq * Fq +
                                  (size_t)(Tq - 1) * Fq + mt * 16 + kg * 4);
    float err_ = 0.f;
    __syncthreads();

    // ===================== decoder: 512 steps, 1 barrier each ============
    for (int k = 0; k < Tq; ++k) {
        const int pk = k & 1;
        f16x8 bf[4];
#pragma unroll
        for (int kt = 0; kt < 4; ++kt)
            bf[kt] = *(const f16x8*)(&hT[pk][zr][kt * 32 + kg * 8]);
        f32x4 acc[4];
#pragma unroll
        for (int g = 0; g < 4; ++g) acc[g] = (f32x4){0.f, 0.f, 0.f, 0.f};
#pragma unroll
        for (int kt = 0; kt < 4; ++kt)
#pragma unroll
            for (int g = 0; g < 4; ++g)
                acc[g] = __builtin_amdgcn_mfma_f32_16x16x32_f16(
                    wc[g][kt], bf[kt], acc[g], 0, 0, 0);
        if (wv >= 4) {   // concurrent projection of h[pk] for rec_err
            f32x4 pacc = (f32x4){0.f, 0.f, 0.f, 0.f};
#pragma unroll
            for (int kt = 0; kt < 4; ++kt)
                pacc = __builtin_amdgcn_mfma_f32_16x16x32_f16(
                    wo[kt], bf[kt], pacc, 0, 0, 0);
            if (act) {
                float a0 = pacc[0] + bo4.x, a1 = pacc[1] + bo4.y;
                float a2 = pacc[2] + bo4.z, a3 = pacc[3] + bo4.w;
                if (k == 0) {
                    float4 av; av.x = a0; av.y = a1; av.z = a2; av.w = a3;
                    *(float4*)(out + (size_t)Bq * Hq + Bq +
                               (size_t)(row0 + n16) * Fq + mt * 16 + kg * 4) = av;
                }
                err_ += fabsf(a0 * a0 - tsv.x * tsv.x);
                err_ += fabsf(a1 * a1 - tsv.y * tsv.y);
                err_ += fabsf(a2 * a2 - tsv.z * tsv.z);
                err_ += fabsf(a3 * a3 - tsv.w * tsv.w);
                if (k < Tq - 1)
                    tsv = *(const float4*)(ts + (size_t)(row0 + n16) * Tq * Fq +
                                           (size_t)(Tq - 2 - k) * Fq +
                                           mt * 16 + kg * 4);
            }
        }
        if (act) {   // LSTM pointwise, D-layout
            f16x4 h4;
#pragma unroll
            for (int r = 0; r < 4; ++r) {
                float i_ = sigmoidf_(acc[0][r] + bias_[0][r]);
                float f_ = sigmoidf_(acc[1][r] + bias_[1][r]);
                float g_ = tanhf_(acc[2][r] + bias_[2][r]);
                float o_ = sigmoidf_(acc[3][r] + bias_[3][r]);
                c_[r] = f_ * c_[r] + i_ * g_;
                h4[r] = (f16)(o_ * tanhf_(c_[r]));
            }
            *(f16x4*)(&hT[pk ^ 1][n16][wv * 16 + kg * 4]) = h4;
        }
        __syncthreads();
    }

    // rec_err reduction: waves 4..7 hold per-(row,f-slice) partials
    if (wv >= 4) {
        err_ += __shfl_xor(err_, 16, 64);   // sum over kg bit 0
        err_ += __shfl_xor(err_, 32, 64);   // sum over kg bit 1
        if (kg == 0 && act) errb[wv - 4][n16] = err_;
    }
    __syncthreads();
    if (tid < 4) {
        float e = errb[0][tid] + errb[1][tid] + errb[2][tid] + errb[3][tid];
        out[(size_t)Bq * Hq + row0 + tid] = e;
    }
}

extern "C" void kernel_launch(void* const* d_in, const int* in_sizes, int n_in,
                              void* d_out, int out_size, void* d_ws, size_t ws_size,
                              hipStream_t stream) {
    const float* ts    = (const float*)d_in[0];
    const float* Wih_e = (const float*)d_in[1];
    const float* Whh_e = (const float*)d_in[2];
    const float* bih_e = (const float*)d_in[3];
    const float* bhh_e = (const float*)d_in[4];
    const float* Wih_d = (const float*)d_in[5];
    const float* Whh_d = (const float*)d_in[6];
    const float* bih_d = (const float*)d_in[7];
    const float* bhh_d = (const float*)d_in[8];
    const float* Wout  = (const float*)d_in[9];
    const float* bout  = (const float*)d_in[10];
    float* out = (float*)d_out;

    dim3 grid(Bq / 4);   // 256 blocks, 4 batch rows each
    dim3 block(512);
    hipLaunchKernelGGL(lstm_ae_kernel, grid, block, 0, stream,
                       ts, Wih_e, Whh_e, bih_e, bhh_e,
                       Wih_d, Whh_d, bih_d, bhh_d, Wout, bout, out);
}

// Round 7
// 1831.137 us; speedup vs baseline: 1.0018x; 1.0018x over previous
//
#include <hip/hip_runtime.h>

// Problem constants
#define Bq 1024
#define Tq 512
#define Fq 64    // input features
#define Hq 128   // hidden

typedef _Float16 f16;
typedef f16 f16x4 __attribute__((ext_vector_type(4)));
typedef f16 f16x8 __attribute__((ext_vector_type(8)));
typedef float f32x4 __attribute__((ext_vector_type(4)));

__device__ __forceinline__ float sigmoidf_(float x) {
    return 1.f / (1.f + __expf(-x));
}
__device__ __forceinline__ float tanhf_(float x) {
    return 1.f - 2.f / (__expf(2.f * x) + 1.f);
}

// 256 blocks x 512 threads (8 waves), 4 batch rows per block, 1 block/CU.
// __launch_bounds__(512,1): grid==CU count, only one block resident per CU
// regardless, so asking for 1 block/CU unlocks the 256-VGPR budget (the
// (512,2) variant capped at 128 VGPR and spilled the decoder weights:
// WRITE_SIZE 33.5 MB of scratch, +680 us).
// Encoder: gates via mfma_f32_16x16x32_f16, M=512 gates (8 waves x 4 tiles:
// wave w owns tiles {w,8+w,16+w,24+w} = i,f,g,o of units 16w..16w+15),
// N=16 (4 real batch cols), K=192 (2 x-tiles + 4 h-tiles).
// D-layout lane (n16<4, kg) holds ALL FOUR gates of units wv*16+kg*4+r in
// acc[0..3][r] -> nonlinearity directly on MFMA output, NO LDS bounce.
// c in registers, h straight to double-buffered hT.
// x staged in 8-step chunks (HBM latency hidden under 8 steps).
// Decoder: x_dec = h@Wout^T + b_out is LINEAR in h -> fold:
//   W_comb = W_ih_dec@W_out + W_hh_dec  (512x128), K=128 only, no x.
// Projection (rec_err only, off the recurrence) runs concurrently on
// waves 4..7 as A=W_out MFMA. ONE barrier per step everywhere.
// LDS strides anti-conflict: hT row 152 f16 (76 dw === 12 mod 32, max
// 2-way = free), xS inner 76 (zr-stride === 16 mod 32, 2-way).
// Frag layouts (validated rounds 4-6):
//   A: lane l holds A[l&15][(l>>4)*8+j]   B: lane l holds B[(l>>4)*8+j][l&15]
//   D: lane l reg r = D[(l>>4)*4+r][l&15]
__global__ __launch_bounds__(512, 1) void lstm_ae_kernel(
    const float* __restrict__ ts,
    const float* __restrict__ Wih_e, const float* __restrict__ Whh_e,
    const float* __restrict__ bih_e, const float* __restrict__ bhh_e,
    const float* __restrict__ Wih_d, const float* __restrict__ Whh_d,
    const float* __restrict__ bih_d, const float* __restrict__ bhh_d,
    const float* __restrict__ Wout, const float* __restrict__ bout,
    float* __restrict__ out)
{
    const int tid = threadIdx.x;
    const int bid = blockIdx.x;
    const int row0 = bid * 4;

    const int wv = tid >> 6;       // wave 0..7
    const int ln = tid & 63;
    const int n16 = ln & 15;       // MFMA N col (batch col; <4 real)
    const int kg = ln >> 4;        // k-group 0..3
    const int zr = n16 & 3;        // aliased batch row for B-fragment
    const bool act = (n16 < 4);

    __shared__ alignas(16) f16 hT[2][4][152];        // h dbuf, 2.4 KB
    __shared__ alignas(16) f16 xS[2][4][8][76];      // x chunk dbuf, 9.5 KB
    __shared__ float errb[4][4];

    float c_[4] = {0.f, 0.f, 0.f, 0.f};
    float bias_[4][4];

    // ===================== encoder setup =====================
    f16x8 wf[4][6];   // A-frags [gate][k-tile], 96 VGPR
#pragma unroll
    for (int g = 0; g < 4; ++g) {
        const int gr = g * 128 + wv * 16 + n16;
#pragma unroll
        for (int kt = 0; kt < 6; ++kt) {
            const int kc = kt * 32 + kg * 8;
            const float* src = (kt < 2)
                ? (Wih_e + (size_t)gr * Fq + kc)
                : (Whh_e + (size_t)gr * Hq + (kc - 64));
            float4 f0 = *(const float4*)src;
            float4 f1 = *(const float4*)(src + 4);
            f16x8 a;
            a[0] = (f16)f0.x; a[1] = (f16)f0.y; a[2] = (f16)f0.z; a[3] = (f16)f0.w;
            a[4] = (f16)f1.x; a[5] = (f16)f1.y; a[6] = (f16)f1.z; a[7] = (f16)f1.w;
            wf[g][kt] = a;
        }
#pragma unroll
        for (int r = 0; r < 4; ++r) {
            const int u = g * 128 + wv * 16 + kg * 4 + r;
            bias_[g][r] = bih_e[u] + bhh_e[u];
        }
    }

    // zero h buffer 0 (same pattern as cell h-write)
    if (act) {
        f16x4 z; z[0] = (f16)0.f; z[1] = (f16)0.f; z[2] = (f16)0.f; z[3] = (f16)0.f;
        *(f16x4*)(&hT[0][n16][wv * 16 + kg * 4]) = z;
    }
    // stage x chunk 0: thread -> (r, t8, fg)
    const int sr = tid >> 7, st8 = (tid >> 4) & 7, sfg = tid & 15;
    {
        float4 v = *(const float4*)(ts + (size_t)(row0 + sr) * Tq * Fq +
                                    (size_t)st8 * Fq + sfg * 4);
        f16x4 h4; h4[0] = (f16)v.x; h4[1] = (f16)v.y; h4[2] = (f16)v.z; h4[3] = (f16)v.w;
        *(f16x4*)(&xS[0][sr][st8][sfg * 4]) = h4;
    }
    __syncthreads();

    // ===================== encoder: 512 steps, 1 barrier each ============
    float4 xpre;
    for (int t = 0; t < Tq; ++t) {
        const int buf = (t >> 3) & 1, tb = t & 7, par = t & 1;
        if (tb == 0 && t < Tq - 8) {   // issue chunk c+1 loads (hidden 8 steps)
            xpre = *(const float4*)(ts + (size_t)(row0 + sr) * Tq * Fq +
                                    (size_t)(t + 8 + st8) * Fq + sfg * 4);
        }
        // cell
        f16x8 bf[6];
        bf[0] = *(const f16x8*)(&xS[buf][zr][tb][kg * 8]);
        bf[1] = *(const f16x8*)(&xS[buf][zr][tb][32 + kg * 8]);
#pragma unroll
        for (int kt = 0; kt < 4; ++kt)
            bf[2 + kt] = *(const f16x8*)(&hT[par][zr][kt * 32 + kg * 8]);
        f32x4 acc[4];
#pragma unroll
        for (int g = 0; g < 4; ++g) acc[g] = (f32x4){0.f, 0.f, 0.f, 0.f};
#pragma unroll
        for (int kt = 0; kt < 6; ++kt)
#pragma unroll
            for (int g = 0; g < 4; ++g)
                acc[g] = __builtin_amdgcn_mfma_f32_16x16x32_f16(
                    wf[g][kt], bf[kt], acc[g], 0, 0, 0);
        if (act) {   // nonlinearity directly in D-layout: 4 units per lane
            f16x4 h4;
#pragma unroll
            for (int r = 0; r < 4; ++r) {
                float i_ = sigmoidf_(acc[0][r] + bias_[0][r]);
                float f_ = sigmoidf_(acc[1][r] + bias_[1][r]);
                float g_ = tanhf_(acc[2][r] + bias_[2][r]);
                float o_ = sigmoidf_(acc[3][r] + bias_[3][r]);
                c_[r] = f_ * c_[r] + i_ * g_;
                h4[r] = (f16)(o_ * tanhf_(c_[r]));
            }
            *(f16x4*)(&hT[par ^ 1][n16][wv * 16 + kg * 4]) = h4;
        }
        if (tb == 7 && t != Tq - 1) {  // publish staged chunk
            f16x4 h4; h4[0] = (f16)xpre.x; h4[1] = (f16)xpre.y;
            h4[2] = (f16)xpre.z; h4[3] = (f16)xpre.w;
            *(f16x4*)(&xS[buf ^ 1][sr][st8][sfg * 4]) = h4;
        }
        __syncthreads();
    }

    // c_enc: lane (n16<4, kg) owns units wv*16+kg*4+0..3 of batch row n16
    if (act) {
        float4 c4; c4.x = c_[0]; c4.y = c_[1]; c4.z = c_[2]; c4.w = c_[3];
        *(float4*)(out + (size_t)(row0 + n16) * Hq + wv * 16 + kg * 4) = c4;
    }

    // ===================== decoder setup (fold) =====================
    // W_comb = W_ih_dec @ W_out + W_hh_dec; b_fold = b_ih+b_hh+W_ih_dec@b_out
    f16x8 wc[4][4];   // 64 VGPR
#pragma unroll
    for (int g = 0; g < 4; ++g) {
        const int gr = g * 128 + wv * 16 + n16;
        float fa[4][8];
#pragma unroll
        for (int kt = 0; kt < 4; ++kt)
#pragma unroll
            for (int jj = 0; jj < 8; ++jj) fa[kt][jj] = 0.f;
        for (int f = 0; f < Fq; ++f) {
            float wv_ = Wih_d[(size_t)gr * Fq + f];
#pragma unroll
            for (int kt = 0; kt < 4; ++kt) {
                float4 o0 = *(const float4*)(Wout + (size_t)f * Hq + kt * 32 + kg * 8);
                float4 o1 = *(const float4*)(Wout + (size_t)f * Hq + kt * 32 + kg * 8 + 4);
                fa[kt][0] += wv_ * o0.x; fa[kt][1] += wv_ * o0.y;
                fa[kt][2] += wv_ * o0.z; fa[kt][3] += wv_ * o0.w;
                fa[kt][4] += wv_ * o1.x; fa[kt][5] += wv_ * o1.y;
                fa[kt][6] += wv_ * o1.z; fa[kt][7] += wv_ * o1.w;
            }
        }
#pragma unroll
        for (int kt = 0; kt < 4; ++kt) {
            f16x8 a;
#pragma unroll
            for (int jj = 0; jj < 8; ++jj)
                a[jj] = (f16)(fa[kt][jj] +
                              Whh_d[(size_t)gr * Hq + kt * 32 + kg * 8 + jj]);
            wc[g][kt] = a;
        }
#pragma unroll
        for (int r = 0; r < 4; ++r) {
            const int u = g * 128 + wv * 16 + kg * 4 + r;
            float b = bih_d[u] + bhh_d[u];
            for (int f = 0; f < Fq; ++f)
                b += Wih_d[(size_t)u * Fq + f] * bout[f];
            bias_[g][r] = b;
        }
    }
    // proj A-frags (waves 4..7 use them; mt=wv&3 keeps addresses valid)
    const int mt = wv & 3;
    f16x8 wo[4];
#pragma unroll
    for (int kt = 0; kt < 4; ++kt) {
        const float* src = Wout + (size_t)(mt * 16 + n16) * Hq + kt * 32 + kg * 8;
        float4 f0 = *(const float4*)src;
        float4 f1 = *(const float4*)(src + 4);
        f16x8 a;
        a[0] = (f16)f0.x; a[1] = (f16)f0.y; a[2] = (f16)f0.z; a[3] = (f16)f0.w;
        a[4] = (f16)f1.x; a[5] = (f16)f1.y; a[6] = (f16)f1.z; a[7] = (f16)f1.w;
        wo[kt] = a;
    }
    float4 bo4 = *(const float4*)(bout + mt * 16 + kg * 4);
    float4 tsv = *(const float4*)(ts + (size_t)(row0 + zr) * Tq * Fq +
                                  (size_t)(Tq - 1) * Fq + mt * 16 + kg * 4);
    float err_ = 0.f;
    __syncthreads();

    // ===================== decoder: 512 steps, 1 barrier each ============
    for (int k = 0; k < Tq; ++k) {
        const int pk = k & 1;
        f16x8 bf[4];
#pragma unroll
        for (int kt = 0; kt < 4; ++kt)
            bf[kt] = *(const f16x8*)(&hT[pk][zr][kt * 32 + kg * 8]);
        f32x4 acc[4];
#pragma unroll
        for (int g = 0; g < 4; ++g) acc[g] = (f32x4){0.f, 0.f, 0.f, 0.f};
#pragma unroll
        for (int kt = 0; kt < 4; ++kt)
#pragma unroll
            for (int g = 0; g < 4; ++g)
                acc[g] = __builtin_amdgcn_mfma_f32_16x16x32_f16(
                    wc[g][kt], bf[kt], acc[g], 0, 0, 0);
        if (wv >= 4) {   // concurrent projection of h[pk] for rec_err
            f32x4 pacc = (f32x4){0.f, 0.f, 0.f, 0.f};
#pragma unroll
            for (int kt = 0; kt < 4; ++kt)
                pacc = __builtin_amdgcn_mfma_f32_16x16x32_f16(
                    wo[kt], bf[kt], pacc, 0, 0, 0);
            if (act) {
                float a0 = pacc[0] + bo4.x, a1 = pacc[1] + bo4.y;
                float a2 = pacc[2] + bo4.z, a3 = pacc[3] + bo4.w;
                if (k == 0) {
                    float4 av; av.x = a0; av.y = a1; av.z = a2; av.w = a3;
                    *(float4*)(out + (size_t)Bq * Hq + Bq +
                               (size_t)(row0 + n16) * Fq + mt * 16 + kg * 4) = av;
                }
                err_ += fabsf(a0 * a0 - tsv.x * tsv.x);
                err_ += fabsf(a1 * a1 - tsv.y * tsv.y);
                err_ += fabsf(a2 * a2 - tsv.z * tsv.z);
                err_ += fabsf(a3 * a3 - tsv.w * tsv.w);
                if (k < Tq - 1)
                    tsv = *(const float4*)(ts + (size_t)(row0 + n16) * Tq * Fq +
                                           (size_t)(Tq - 2 - k) * Fq +
                                           mt * 16 + kg * 4);
            }
        }
        if (act) {   // LSTM pointwise, D-layout
            f16x4 h4;
#pragma unroll
            for (int r = 0; r < 4; ++r) {
                float i_ = sigmoidf_(acc[0][r] + bias_[0][r]);
                float f_ = sigmoidf_(acc[1][r] + bias_[1][r]);
                float g_ = tanhf_(acc[2][r] + bias_[2][r]);
                float o_ = sigmoidf_(acc[3][r] + bias_[3][r]);
                c_[r] = f_ * c_[r] + i_ * g_;
                h4[r] = (f16)(o_ * tanhf_(c_[r]));
            }
            *(f16x4*)(&hT[pk ^ 1][n16][wv * 16 + kg * 4]) = h4;
        }
        __syncthreads();
    }

    // rec_err reduction: waves 4..7 hold per-(row,f-slice) partials
    if (wv >= 4) {
        err_ += __shfl_xor(err_, 16, 64);   // sum over kg bit 0
        err_ += __shfl_xor(err_, 32, 64);   // sum over kg bit 1
        if (kg == 0 && act) errb[wv - 4][n16] = err_;
    }
    __syncthreads();
    if (tid < 4) {
        float e = errb[0][tid] + errb[1][tid] + errb[2][tid] + errb[3][tid];
        out[(size_t)Bq * Hq + row0 + tid] = e;
    }
}

extern "C" void kernel_launch(void* const* d_in, const int* in_sizes, int n_in,
                              void* d_out, int out_size, void* d_ws, size_t ws_size,
                              hipStream_t stream) {
    const float* ts    = (const float*)d_in[0];
    const float* Wih_e = (const float*)d_in[1];
    const float* Whh_e = (const float*)d_in[2];
    const float* bih_e = (const float*)d_in[3];
    const float* bhh_e = (const float*)d_in[4];
    const float* Wih_d = (const float*)d_in[5];
    const float* Whh_d = (const float*)d_in[6];
    const float* bih_d = (const float*)d_in[7];
    const float* bhh_d = (const float*)d_in[8];
    const float* Wout  = (const float*)d_in[9];
    const float* bout  = (const float*)d_in[10];
    float* out = (float*)d_out;

    dim3 grid(Bq / 4);   // 256 blocks, 4 batch rows each
    dim3 block(512);
    hipLaunchKernelGGL(lstm_ae_kernel, grid, block, 0, stream,
                       ts, Wih_e, Whh_e, bih_e, bhh_e,
                       Wih_d, Whh_d, bih_d, bhh_d, Wout, bout, out);
}

// Round 8
// 1667.321 us; speedup vs baseline: 1.1002x; 1.0983x over previous
//
#include <hip/hip_runtime.h>

// Problem constants
#define Bq 1024
#define Tq 512
#define Fq 64    // input features
#define Hq 128   // hidden

typedef _Float16 f16;
typedef f16 f16x2 __attribute__((ext_vector_type(2)));
typedef f16 f16x4 __attribute__((ext_vector_type(4)));
typedef f16 f16x8 __attribute__((ext_vector_type(8)));
typedef float f32x4 __attribute__((ext_vector_type(4)));

__device__ __forceinline__ float sigmoidf_(float x) {
    return 1.f / (1.f + __expf(-x));
}
__device__ __forceinline__ float tanhf_(float x) {
    return 1.f - 2.f / (__expf(2.f * x) + 1.f);
}

// ---------------- kernel A: decoder fold (one-time, tiny) ----------------
// W_comb = W_ih_dec @ W_out + W_hh_dec   (f16, [512][128])
// b_fold = b_ih_dec + b_hh_dec + W_ih_dec @ b_out   (f32, [512])
// Removing this from the main kernel kills the fa[32]-register fold loop
// that caused 33.5 MB of scratch spill traffic in rounds 6-7.
__global__ __launch_bounds__(256) void fold_kernel(
    const float* __restrict__ Wih_d, const float* __restrict__ Whh_d,
    const float* __restrict__ bih_d, const float* __restrict__ bhh_d,
    const float* __restrict__ Wout, const float* __restrict__ bout,
    f16* __restrict__ Wcomb, float* __restrict__ bfold)
{
    const int gid = blockIdx.x * 256 + threadIdx.x;   // 0..32767
    const int og = gid >> 6;          // gate row 0..511
    const int oh = (gid & 63) * 2;    // hh pair
    float ax = Whh_d[(size_t)og * Hq + oh];
    float ay = Whh_d[(size_t)og * Hq + oh + 1];
    for (int f = 0; f < Fq; ++f) {
        float w = Wih_d[(size_t)og * Fq + f];
        float2 o = *(const float2*)(Wout + (size_t)f * Hq + oh);
        ax += w * o.x; ay += w * o.y;
    }
    f16x2 r; r.x = (f16)ax; r.y = (f16)ay;
    *(f16x2*)(Wcomb + (size_t)og * Hq + oh) = r;
    if (gid < 512) {
        float b = bih_d[gid] + bhh_d[gid];
        for (int f = 0; f < Fq; ++f)
            b += Wih_d[(size_t)gid * Fq + f] * bout[f];
        bfold[gid] = b;
    }
}

// ---------------- kernel B: main recurrence ----------------
// 256 blocks x 512 threads (8 waves), 4 batch rows per block, 1 block/CU.
// Structure as round 7 (D-layout nonlinearity, folded decoder, concurrent
// proj on waves 4-7, 1 barrier/step) with the register diet:
//  - bias lives in LDS, applied as MFMA C-init via broadcast ds_read (-16)
//  - decoder wc loaded as 16 direct 16B loads from ws (fold pre-kernel)
//  - no fa[] fold loop in-kernel
// Frag layouts (validated rounds 4-7):
//   A: lane l holds A[l&15][(l>>4)*8+j]   B: lane l holds B[(l>>4)*8+j][l&15]
//   D: lane l reg r = D[(l>>4)*4+r][l&15]
__global__ __launch_bounds__(512)
__attribute__((amdgpu_waves_per_eu(2)))
void lstm_ae_kernel(
    const float* __restrict__ ts,
    const float* __restrict__ Wih_e, const float* __restrict__ Whh_e,
    const float* __restrict__ bih_e, const float* __restrict__ bhh_e,
    const float* __restrict__ Wout, const float* __restrict__ bout,
    const f16* __restrict__ Wcomb, const float* __restrict__ bfold,
    float* __restrict__ out)
{
    const int tid = threadIdx.x;
    const int bid = blockIdx.x;
    const int row0 = bid * 4;

    const int wv = tid >> 6;       // wave 0..7
    const int ln = tid & 63;
    const int n16 = ln & 15;       // MFMA N col (batch col; <4 real)
    const int kg = ln >> 4;        // k-group 0..3
    const int zr = n16 & 3;        // aliased batch row for B-fragment
    const bool act = (n16 < 4);

    __shared__ alignas(16) f16 hT[2][4][144];        // h dbuf (zr stride 8 mod 32 dw)
    __shared__ alignas(16) f16 xS[2][4][8][76];      // x chunk dbuf
    __shared__ alignas(16) float bias_lds[8][4][16]; // 2 KB, C-init bias
    __shared__ float errb[4][4];

    float c_[4] = {0.f, 0.f, 0.f, 0.f};

    // ===================== encoder setup =====================
    f16x8 wf[4][6];   // A-frags [gate][k-tile], 96 VGPR
#pragma unroll
    for (int g = 0; g < 4; ++g) {
        const int gr = g * 128 + wv * 16 + n16;
#pragma unroll
        for (int kt = 0; kt < 6; ++kt) {
            const int kc = kt * 32 + kg * 8;
            const float* src = (kt < 2)
                ? (Wih_e + (size_t)gr * Fq + kc)
                : (Whh_e + (size_t)gr * Hq + (kc - 64));
            float4 f0 = *(const float4*)src;
            float4 f1 = *(const float4*)(src + 4);
            f16x8 a;
            a[0] = (f16)f0.x; a[1] = (f16)f0.y; a[2] = (f16)f0.z; a[3] = (f16)f0.w;
            a[4] = (f16)f1.x; a[5] = (f16)f1.y; a[6] = (f16)f1.z; a[7] = (f16)f1.w;
            wf[g][kt] = a;
        }
    }
    if (tid < 512) {   // bias -> LDS (encoder)
        const int w2 = tid >> 6, rest = tid & 63, g2 = rest >> 4, j = rest & 15;
        const int u = g2 * 128 + w2 * 16 + j;
        bias_lds[w2][g2][j] = bih_e[u] + bhh_e[u];
    }
    // zero h buffer 0
    if (act) {
        f16x4 z; z[0] = (f16)0.f; z[1] = (f16)0.f; z[2] = (f16)0.f; z[3] = (f16)0.f;
        *(f16x4*)(&hT[0][n16][wv * 16 + kg * 4]) = z;
    }
    // stage x chunk 0: thread -> (r, t8, fg)
    const int sr = tid >> 7, st8 = (tid >> 4) & 7, sfg = tid & 15;
    {
        float4 v = *(const float4*)(ts + (size_t)(row0 + sr) * Tq * Fq +
                                    (size_t)st8 * Fq + sfg * 4);
        f16x4 h4; h4[0] = (f16)v.x; h4[1] = (f16)v.y; h4[2] = (f16)v.z; h4[3] = (f16)v.w;
        *(f16x4*)(&xS[0][sr][st8][sfg * 4]) = h4;
    }
    __syncthreads();

    // ===================== encoder: 512 steps, 1 barrier each ============
    float4 xpre;
    for (int t = 0; t < Tq; ++t) {
        const int buf = (t >> 3) & 1, tb = t & 7, par = t & 1;
        if (tb == 0 && t < Tq - 8) {   // issue chunk c+1 loads (hidden 8 steps)
            xpre = *(const float4*)(ts + (size_t)(row0 + sr) * Tq * Fq +
                                    (size_t)(t + 8 + st8) * Fq + sfg * 4);
        }
        f16x8 bf[6];
        bf[0] = *(const f16x8*)(&xS[buf][zr][tb][kg * 8]);
        bf[1] = *(const f16x8*)(&xS[buf][zr][tb][32 + kg * 8]);
#pragma unroll
        for (int kt = 0; kt < 4; ++kt)
            bf[2 + kt] = *(const f16x8*)(&hT[par][zr][kt * 32 + kg * 8]);
        f32x4 acc[4];
#pragma unroll
        for (int g = 0; g < 4; ++g)      // bias as C-init (broadcast read)
            acc[g] = *(const f32x4*)(&bias_lds[wv][g][kg * 4]);
#pragma unroll
        for (int kt = 0; kt < 6; ++kt)
#pragma unroll
            for (int g = 0; g < 4; ++g)
                acc[g] = __builtin_amdgcn_mfma_f32_16x16x32_f16(
                    wf[g][kt], bf[kt], acc[g], 0, 0, 0);
        if (act) {   // nonlinearity directly in D-layout: 4 units per lane
            f16x4 h4;
#pragma unroll
            for (int r = 0; r < 4; ++r) {
                float i_ = sigmoidf_(acc[0][r]);
                float f_ = sigmoidf_(acc[1][r]);
                float g_ = tanhf_(acc[2][r]);
                float o_ = sigmoidf_(acc[3][r]);
                c_[r] = f_ * c_[r] + i_ * g_;
                h4[r] = (f16)(o_ * tanhf_(c_[r]));
            }
            *(f16x4*)(&hT[par ^ 1][n16][wv * 16 + kg * 4]) = h4;
        }
        if (tb == 7 && t != Tq - 1) {  // publish staged chunk
            f16x4 h4; h4[0] = (f16)xpre.x; h4[1] = (f16)xpre.y;
            h4[2] = (f16)xpre.z; h4[3] = (f16)xpre.w;
            *(f16x4*)(&xS[buf ^ 1][sr][st8][sfg * 4]) = h4;
        }
        __syncthreads();
    }

    // c_enc: lane (n16<4, kg) owns units wv*16+kg*4+0..3 of batch row n16
    if (act) {
        float4 c4; c4.x = c_[0]; c4.y = c_[1]; c4.z = c_[2]; c4.w = c_[3];
        *(float4*)(out + (size_t)(row0 + n16) * Hq + wv * 16 + kg * 4) = c4;
    }

    // ===================== decoder setup =====================
    f16x8 wc[4][4];   // folded weights straight from ws: 16 x 16B loads
#pragma unroll
    for (int g = 0; g < 4; ++g) {
        const int gr = g * 128 + wv * 16 + n16;
#pragma unroll
        for (int kt = 0; kt < 4; ++kt)
            wc[g][kt] = *(const f16x8*)(Wcomb + (size_t)gr * Hq + kt * 32 + kg * 8);
    }
    if (tid < 512) {   // bias_lds <- b_fold (safe: past loop-final barrier)
        const int w2 = tid >> 6, rest = tid & 63, g2 = rest >> 4, j = rest & 15;
        bias_lds[w2][g2][j] = bfold[g2 * 128 + w2 * 16 + j];
    }
    // proj A-frags (waves 4..7 use them; mt=wv&3 keeps addresses valid)
    const int mt = wv & 3;
    f16x8 wo[4];
#pragma unroll
    for (int kt = 0; kt < 4; ++kt) {
        const float* src = Wout + (size_t)(mt * 16 + n16) * Hq + kt * 32 + kg * 8;
        float4 f0 = *(const float4*)src;
        float4 f1 = *(const float4*)(src + 4);
        f16x8 a;
        a[0] = (f16)f0.x; a[1] = (f16)f0.y; a[2] = (f16)f0.z; a[3] = (f16)f0.w;
        a[4] = (f16)f1.x; a[5] = (f16)f1.y; a[6] = (f16)f1.z; a[7] = (f16)f1.w;
        wo[kt] = a;
    }
    float4 bo4 = *(const float4*)(bout + mt * 16 + kg * 4);
    float4 tsv = *(const float4*)(ts + (size_t)(row0 + zr) * Tq * Fq +
                                  (size_t)(Tq - 1) * Fq + mt * 16 + kg * 4);
    float err_ = 0.f;
    __syncthreads();

    // ===================== decoder: 512 steps, 1 barrier each ============
    for (int k = 0; k < Tq; ++k) {
        const int pk = k & 1;
        f16x8 bf[4];
#pragma unroll
        for (int kt = 0; kt < 4; ++kt)
            bf[kt] = *(const f16x8*)(&hT[pk][zr][kt * 32 + kg * 8]);
        f32x4 acc[4];
#pragma unroll
        for (int g = 0; g < 4; ++g)
            acc[g] = *(const f32x4*)(&bias_lds[wv][g][kg * 4]);
#pragma unroll
        for (int kt = 0; kt < 4; ++kt)
#pragma unroll
            for (int g = 0; g < 4; ++g)
                acc[g] = __builtin_amdgcn_mfma_f32_16x16x32_f16(
                    wc[g][kt], bf[kt], acc[g], 0, 0, 0);
        if (wv >= 4) {   // concurrent projection of h[pk] for rec_err
            f32x4 pacc = (f32x4){0.f, 0.f, 0.f, 0.f};
#pragma unroll
            for (int kt = 0; kt < 4; ++kt)
                pacc = __builtin_amdgcn_mfma_f32_16x16x32_f16(
                    wo[kt], bf[kt], pacc, 0, 0, 0);
            if (act) {
                float a0 = pacc[0] + bo4.x, a1 = pacc[1] + bo4.y;
                float a2 = pacc[2] + bo4.z, a3 = pacc[3] + bo4.w;
                if (k == 0) {
                    float4 av; av.x = a0; av.y = a1; av.z = a2; av.w = a3;
                    *(float4*)(out + (size_t)Bq * Hq + Bq +
                               (size_t)(row0 + n16) * Fq + mt * 16 + kg * 4) = av;
                }
                err_ += fabsf(a0 * a0 - tsv.x * tsv.x);
                err_ += fabsf(a1 * a1 - tsv.y * tsv.y);
                err_ += fabsf(a2 * a2 - tsv.z * tsv.z);
                err_ += fabsf(a3 * a3 - tsv.w * tsv.w);
                if (k < Tq - 1)
                    tsv = *(const float4*)(ts + (size_t)(row0 + n16) * Tq * Fq +
                                           (size_t)(Tq - 2 - k) * Fq +
                                           mt * 16 + kg * 4);
            }
        }
        if (act) {   // LSTM pointwise, D-layout
            f16x4 h4;
#pragma unroll
            for (int r = 0; r < 4; ++r) {
                float i_ = sigmoidf_(acc[0][r]);
                float f_ = sigmoidf_(acc[1][r]);
                float g_ = tanhf_(acc[2][r]);
                float o_ = sigmoidf_(acc[3][r]);
                c_[r] = f_ * c_[r] + i_ * g_;
                h4[r] = (f16)(o_ * tanhf_(c_[r]));
            }
            *(f16x4*)(&hT[pk ^ 1][n16][wv * 16 + kg * 4]) = h4;
        }
        __syncthreads();
    }

    // rec_err reduction: waves 4..7 hold per-(row,f-slice) partials
    if (wv >= 4) {
        err_ += __shfl_xor(err_, 16, 64);   // sum over kg bit 0
        err_ += __shfl_xor(err_, 32, 64);   // sum over kg bit 1
        if (kg == 0 && act) errb[wv - 4][n16] = err_;
    }
    __syncthreads();
    if (tid < 4) {
        float e = errb[0][tid] + errb[1][tid] + errb[2][tid] + errb[3][tid];
        out[(size_t)Bq * Hq + row0 + tid] = e;
    }
}

extern "C" void kernel_launch(void* const* d_in, const int* in_sizes, int n_in,
                              void* d_out, int out_size, void* d_ws, size_t ws_size,
                              hipStream_t stream) {
    const float* ts    = (const float*)d_in[0];
    const float* Wih_e = (const float*)d_in[1];
    const float* Whh_e = (const float*)d_in[2];
    const float* bih_e = (const float*)d_in[3];
    const float* bhh_e = (const float*)d_in[4];
    const float* Wih_d = (const float*)d_in[5];
    const float* Whh_d = (const float*)d_in[6];
    const float* bih_d = (const float*)d_in[7];
    const float* bhh_d = (const float*)d_in[8];
    const float* Wout  = (const float*)d_in[9];
    const float* bout  = (const float*)d_in[10];
    float* out = (float*)d_out;

    f16*   Wcomb = (f16*)d_ws;                                   // 128 KB
    float* bfold = (float*)((char*)d_ws + (size_t)512 * 128 * 2); // +2 KB

    hipLaunchKernelGGL(fold_kernel, dim3(128), dim3(256), 0, stream,
                       Wih_d, Whh_d, bih_d, bhh_d, Wout, bout, Wcomb, bfold);
    hipLaunchKernelGGL(lstm_ae_kernel, dim3(Bq / 4), dim3(512), 0, stream,
                       ts, Wih_e, Whh_e, bih_e, bhh_e,
                       Wout, bout, Wcomb, bfold, out);
}

// Round 9
// 868.435 us; speedup vs baseline: 2.1124x; 1.9199x over previous
//
#include <hip/hip_runtime.h>

// Problem constants
#define Bq 1024
#define Tq 512
#define Fq 64    // input features
#define Hq 128   // hidden

typedef _Float16 f16;
typedef f16 f16x2 __attribute__((ext_vector_type(2)));
typedef f16 f16x4 __attribute__((ext_vector_type(4)));
typedef f16 f16x8 __attribute__((ext_vector_type(8)));
typedef float f32x4 __attribute__((ext_vector_type(4)));

__device__ __forceinline__ float sigmoidf_(float x) {
    return 1.f / (1.f + __expf(-x));
}
__device__ __forceinline__ float tanhf_(float x) {
    return 1.f - 2.f / (__expf(2.f * x) + 1.f);
}

// ---------------- kernel A: decoder fold (one-time, tiny) ----------------
// W_comb = W_ih_dec @ W_out + W_hh_dec   (f16, [512][128])
// b_fold = b_ih_dec + b_hh_dec + W_ih_dec @ b_out   (f32, [512])
__global__ __launch_bounds__(256) void fold_kernel(
    const float* __restrict__ Wih_d, const float* __restrict__ Whh_d,
    const float* __restrict__ bih_d, const float* __restrict__ bhh_d,
    const float* __restrict__ Wout, const float* __restrict__ bout,
    f16* __restrict__ Wcomb, float* __restrict__ bfold)
{
    const int gid = blockIdx.x * 256 + threadIdx.x;   // 0..32767
    const int og = gid >> 6;          // gate row 0..511
    const int oh = (gid & 63) * 2;    // hh pair
    float ax = Whh_d[(size_t)og * Hq + oh];
    float ay = Whh_d[(size_t)og * Hq + oh + 1];
    for (int f = 0; f < Fq; ++f) {
        float w = Wih_d[(size_t)og * Fq + f];
        float2 o = *(const float2*)(Wout + (size_t)f * Hq + oh);
        ax += w * o.x; ay += w * o.y;
    }
    f16x2 r; r.x = (f16)ax; r.y = (f16)ay;
    *(f16x2*)(Wcomb + (size_t)og * Hq + oh) = r;
    if (gid < 512) {
        float b = bih_d[gid] + bhh_d[gid];
        for (int f = 0; f < Fq; ++f)
            b += Wih_d[(size_t)gid * Fq + f] * bout[f];
        bfold[gid] = b;
    }
}

// ---------------- kernel B: main recurrence ----------------
// 256 blocks x 512 threads (8 waves), 4 batch rows per block.
// Hybrid of round-5 (wave-private gscr bounce -> ALL 64 lanes run ONE
// unit's nonlinearity each; VALUBusy 39% there vs 73% for the 16-lane
// D-layout pointwise of round 8) and round-8 (fold pre-kernel, K=128
// decoder, 1 barrier/step, anti-conflict strides, no spills).
// Bias is a per-thread scalar add after the bounce (no C-init LDS reads).
// Frag layouts (validated rounds 4-8):
//   A: lane l holds A[l&15][(l>>4)*8+j]   B: lane l holds B[(l>>4)*8+j][l&15]
//   D: lane l reg r = D[(l>>4)*4+r][l&15]
__global__ __launch_bounds__(512)
__attribute__((amdgpu_waves_per_eu(2)))
void lstm_ae_kernel(
    const float* __restrict__ ts,
    const float* __restrict__ Wih_e, const float* __restrict__ Whh_e,
    const float* __restrict__ bih_e, const float* __restrict__ bhh_e,
    const float* __restrict__ Wout, const float* __restrict__ bout,
    const f16* __restrict__ Wcomb, const float* __restrict__ bfold,
    float* __restrict__ out)
{
    const int tid = threadIdx.x;
    const int bid = blockIdx.x;
    const int row0 = bid * 4;

    const int wv = tid >> 6;       // wave 0..7
    const int ln = tid & 63;
    const int n16 = ln & 15;       // MFMA N col (batch col; <4 real)
    const int kg = ln >> 4;        // k-group 0..3
    const int zr = n16 & 3;        // aliased batch row for B-fragment
    const bool act = (n16 < 4);
    const int ul = ln >> 2;        // pointwise: unit-sub 0..15
    const int cl = ln & 3;         // pointwise: batch col 0..3

    __shared__ alignas(16) f16 hT[2][4][144];        // h dbuf
    __shared__ alignas(16) f16 xS[2][4][8][76];      // x chunk dbuf
    __shared__ alignas(16) float gscr[8][4][4][16];  // 8 KB wave-private bounce
    __shared__ float errb[4][4];

    float c_ = 0.f;    // one unit (wv*16+ul), one batch col (cl)
    float bs[4];       // bias for that unit, gates i,f,g,o

    // ===================== encoder setup =====================
    f16x8 wf[4][6];   // A-frags [gate][k-tile], 96 VGPR
#pragma unroll
    for (int g = 0; g < 4; ++g) {
        const int gr = g * 128 + wv * 16 + n16;
#pragma unroll
        for (int kt = 0; kt < 6; ++kt) {
            const int kc = kt * 32 + kg * 8;
            const float* src = (kt < 2)
                ? (Wih_e + (size_t)gr * Fq + kc)
                : (Whh_e + (size_t)gr * Hq + (kc - 64));
            float4 f0 = *(const float4*)src;
            float4 f1 = *(const float4*)(src + 4);
            f16x8 a;
            a[0] = (f16)f0.x; a[1] = (f16)f0.y; a[2] = (f16)f0.z; a[3] = (f16)f0.w;
            a[4] = (f16)f1.x; a[5] = (f16)f1.y; a[6] = (f16)f1.z; a[7] = (f16)f1.w;
            wf[g][kt] = a;
        }
        bs[g] = bih_e[g * 128 + wv * 16 + ul] + bhh_e[g * 128 + wv * 16 + ul];
    }

    // zero h buffer 0
    if (act) {
        f16x4 z; z[0] = (f16)0.f; z[1] = (f16)0.f; z[2] = (f16)0.f; z[3] = (f16)0.f;
        *(f16x4*)(&hT[0][n16][wv * 16 + kg * 4]) = z;
    }
    // stage x chunk 0: thread -> (r, t8, fg)
    const int sr = tid >> 7, st8 = (tid >> 4) & 7, sfg = tid & 15;
    {
        float4 v = *(const float4*)(ts + (size_t)(row0 + sr) * Tq * Fq +
                                    (size_t)st8 * Fq + sfg * 4);
        f16x4 h4; h4[0] = (f16)v.x; h4[1] = (f16)v.y; h4[2] = (f16)v.z; h4[3] = (f16)v.w;
        *(f16x4*)(&xS[0][sr][st8][sfg * 4]) = h4;
    }
    __syncthreads();

    // ===================== encoder: 512 steps, 1 barrier each ============
    float4 xpre;
    for (int t = 0; t < Tq; ++t) {
        const int buf = (t >> 3) & 1, tb = t & 7, par = t & 1;
        if (tb == 0 && t < Tq - 8) {   // issue chunk c+1 loads (hidden 8 steps)
            xpre = *(const float4*)(ts + (size_t)(row0 + sr) * Tq * Fq +
                                    (size_t)(t + 8 + st8) * Fq + sfg * 4);
        }
        f16x8 bf[6];
        bf[0] = *(const f16x8*)(&xS[buf][zr][tb][kg * 8]);
        bf[1] = *(const f16x8*)(&xS[buf][zr][tb][32 + kg * 8]);
#pragma unroll
        for (int kt = 0; kt < 4; ++kt)
            bf[2 + kt] = *(const f16x8*)(&hT[par][zr][kt * 32 + kg * 8]);
        f32x4 acc[4];
#pragma unroll
        for (int g = 0; g < 4; ++g) acc[g] = (f32x4){0.f, 0.f, 0.f, 0.f};
#pragma unroll
        for (int kt = 0; kt < 6; ++kt)
#pragma unroll
            for (int g = 0; g < 4; ++g)
                acc[g] = __builtin_amdgcn_mfma_f32_16x16x32_f16(
                    wf[g][kt], bf[kt], acc[g], 0, 0, 0);
        // wave-private bounce: D rows kg*4+r, col n16 -> [gate][col][unit]
        if (act) {
#pragma unroll
            for (int g = 0; g < 4; ++g)
                *(f32x4*)(&gscr[wv][g][n16][kg * 4]) = acc[g];
        }
        asm volatile("s_waitcnt lgkmcnt(0)" ::: "memory");
        __builtin_amdgcn_sched_barrier(0);
        {   // all 64 lanes: one unit each
            float gi = gscr[wv][0][cl][ul] + bs[0];
            float gf = gscr[wv][1][cl][ul] + bs[1];
            float gg = gscr[wv][2][cl][ul] + bs[2];
            float go = gscr[wv][3][cl][ul] + bs[3];
            float i_ = sigmoidf_(gi);
            float f_ = sigmoidf_(gf);
            float g_ = tanhf_(gg);
            float o_ = sigmoidf_(go);
            c_ = f_ * c_ + i_ * g_;
            hT[par ^ 1][cl][wv * 16 + ul] = (f16)(o_ * tanhf_(c_));
        }
        if (tb == 7 && t != Tq - 1) {  // publish staged chunk
            f16x4 h4; h4[0] = (f16)xpre.x; h4[1] = (f16)xpre.y;
            h4[2] = (f16)xpre.z; h4[3] = (f16)xpre.w;
            *(f16x4*)(&xS[buf ^ 1][sr][st8][sfg * 4]) = h4;
        }
        __syncthreads();
    }

    // c_enc: thread owns unit wv*16+ul of batch row cl
    out[(size_t)(row0 + cl) * Hq + wv * 16 + ul] = c_;

    // ===================== decoder setup =====================
    f16x8 wc[4][4];   // folded weights straight from ws: 16 x 16B loads
#pragma unroll
    for (int g = 0; g < 4; ++g) {
        const int gr = g * 128 + wv * 16 + n16;
#pragma unroll
        for (int kt = 0; kt < 4; ++kt)
            wc[g][kt] = *(const f16x8*)(Wcomb + (size_t)gr * Hq + kt * 32 + kg * 8);
        bs[g] = bfold[g * 128 + wv * 16 + ul];
    }
    // proj A-frags (waves 4..7 use them; mt=wv&3 keeps addresses valid)
    const int mt = wv & 3;
    f16x8 wo[4];
#pragma unroll
    for (int kt = 0; kt < 4; ++kt) {
        const float* src = Wout + (size_t)(mt * 16 + n16) * Hq + kt * 32 + kg * 8;
        float4 f0 = *(const float4*)src;
        float4 f1 = *(const float4*)(src + 4);
        f16x8 a;
        a[0] = (f16)f0.x; a[1] = (f16)f0.y; a[2] = (f16)f0.z; a[3] = (f16)f0.w;
        a[4] = (f16)f1.x; a[5] = (f16)f1.y; a[6] = (f16)f1.z; a[7] = (f16)f1.w;
        wo[kt] = a;
    }
    float4 bo4 = *(const float4*)(bout + mt * 16 + kg * 4);
    float4 tsv = *(const float4*)(ts + (size_t)(row0 + zr) * Tq * Fq +
                                  (size_t)(Tq - 1) * Fq + mt * 16 + kg * 4);
    float err_ = 0.f;
    __syncthreads();

    // ===================== decoder: 512 steps, 1 barrier each ============
    for (int k = 0; k < Tq; ++k) {
        const int pk = k & 1;
        f16x8 bf[4];
#pragma unroll
        for (int kt = 0; kt < 4; ++kt)
            bf[kt] = *(const f16x8*)(&hT[pk][zr][kt * 32 + kg * 8]);
        f32x4 acc[4];
#pragma unroll
        for (int g = 0; g < 4; ++g) acc[g] = (f32x4){0.f, 0.f, 0.f, 0.f};
#pragma unroll
        for (int kt = 0; kt < 4; ++kt)
#pragma unroll
            for (int g = 0; g < 4; ++g)
                acc[g] = __builtin_amdgcn_mfma_f32_16x16x32_f16(
                    wc[g][kt], bf[kt], acc[g], 0, 0, 0);
        if (wv >= 4) {   // concurrent projection of h[pk] for rec_err
            f32x4 pacc = (f32x4){0.f, 0.f, 0.f, 0.f};
#pragma unroll
            for (int kt = 0; kt < 4; ++kt)
                pacc = __builtin_amdgcn_mfma_f32_16x16x32_f16(
                    wo[kt], bf[kt], pacc, 0, 0, 0);
            if (act) {
                float a0 = pacc[0] + bo4.x, a1 = pacc[1] + bo4.y;
                float a2 = pacc[2] + bo4.z, a3 = pacc[3] + bo4.w;
                if (k == 0) {
                    float4 av; av.x = a0; av.y = a1; av.z = a2; av.w = a3;
                    *(float4*)(out + (size_t)Bq * Hq + Bq +
                               (size_t)(row0 + n16) * Fq + mt * 16 + kg * 4) = av;
                }
                err_ += fabsf(a0 * a0 - tsv.x * tsv.x);
                err_ += fabsf(a1 * a1 - tsv.y * tsv.y);
                err_ += fabsf(a2 * a2 - tsv.z * tsv.z);
                err_ += fabsf(a3 * a3 - tsv.w * tsv.w);
                if (k < Tq - 1)
                    tsv = *(const float4*)(ts + (size_t)(row0 + n16) * Tq * Fq +
                                           (size_t)(Tq - 2 - k) * Fq +
                                           mt * 16 + kg * 4);
            }
        }
        if (act) {
#pragma unroll
            for (int g = 0; g < 4; ++g)
                *(f32x4*)(&gscr[wv][g][n16][kg * 4]) = acc[g];
        }
        asm volatile("s_waitcnt lgkmcnt(0)" ::: "memory");
        __builtin_amdgcn_sched_barrier(0);
        {
            float gi = gscr[wv][0][cl][ul] + bs[0];
            float gf = gscr[wv][1][cl][ul] + bs[1];
            float gg = gscr[wv][2][cl][ul] + bs[2];
            float go = gscr[wv][3][cl][ul] + bs[3];
            float i_ = sigmoidf_(gi);
            float f_ = sigmoidf_(gf);
            float g_ = tanhf_(gg);
            float o_ = sigmoidf_(go);
            c_ = f_ * c_ + i_ * g_;
            hT[pk ^ 1][cl][wv * 16 + ul] = (f16)(o_ * tanhf_(c_));
        }
        __syncthreads();
    }

    // rec_err reduction: waves 4..7 hold per-(row,f-slice) partials
    if (wv >= 4) {
        err_ += __shfl_xor(err_, 16, 64);   // sum over kg bit 0
        err_ += __shfl_xor(err_, 32, 64);   // sum over kg bit 1
        if (kg == 0 && act) errb[wv - 4][n16] = err_;
    }
    __syncthreads();
    if (tid < 4) {
        float e = errb[0][tid] + errb[1][tid] + errb[2][tid] + errb[3][tid];
        out[(size_t)Bq * Hq + row0 + tid] = e;
    }
}

extern "C" void kernel_launch(void* const* d_in, const int* in_sizes, int n_in,
                              void* d_out, int out_size, void* d_ws, size_t ws_size,
                              hipStream_t stream) {
    const float* ts    = (const float*)d_in[0];
    const float* Wih_e = (const float*)d_in[1];
    const float* Whh_e = (const float*)d_in[2];
    const float* bih_e = (const float*)d_in[3];
    const float* bhh_e = (const float*)d_in[4];
    const float* Wih_d = (const float*)d_in[5];
    const float* Whh_d = (const float*)d_in[6];
    const float* bih_d = (const float*)d_in[7];
    const float* bhh_d = (const float*)d_in[8];
    const float* Wout  = (const float*)d_in[9];
    const float* bout  = (const float*)d_in[10];
    float* out = (float*)d_out;

    f16*   Wcomb = (f16*)d_ws;                                   // 128 KB
    float* bfold = (float*)((char*)d_ws + (size_t)512 * 128 * 2); // +2 KB

    hipLaunchKernelGGL(fold_kernel, dim3(128), dim3(256), 0, stream,
                       Wih_d, Whh_d, bih_d, bhh_d, Wout, bout, Wcomb, bfold);
    hipLaunchKernelGGL(lstm_ae_kernel, dim3(Bq / 4), dim3(512), 0, stream,
                       ts, Wih_e, Whh_e, bih_e, bhh_e,
                       Wout, bout, Wcomb, bfold, out);
}